// Round 2
// baseline (2291.553 us; speedup 1.0000x reference)
//
#include <hip/hip_runtime.h>
#include <hip/hip_bf16.h>

// SLSTM (plain LSTM recurrence) + final Linear.  B=1024, T=2048, IN=16, H=128, OUT=1.
// Persistent kernel: 64 WGs x 512 threads; WG owns 16 batch rows for all T steps.
// TRANSPOSED GEMM vs R1: gates^T (512x16) = W' (512x160) @ [h|x]^T (160x16),
// mfma_f32_16x16x32_bf16 with A=weights (static, in regs), B=[h|x] fragment.
// Wave w owns M-tiles {w, w+8, w+16, w+24} = i,f,g,o rows for the same h-cols ->
// elementwise + c state in registers. D: row=gate (quad*4+r), col=batch (c16).
// h stored in LDS in FRAGMENT ORDER: element(kf,quad,c16,j) at ((kf*4+quad)*16+c16)*8+j
// -> reads are lane-contiguous b128 (conflict-free), writes one b64/lane (conflict-free).

#define T_LEN 2048
#define IN_DIM 16
#define H_DIM 128

typedef __attribute__((ext_vector_type(4))) float f32x4;
typedef __attribute__((ext_vector_type(8))) short s16x8;
typedef __attribute__((ext_vector_type(4))) short s16x4;

__device__ __forceinline__ short f2bf(float f) {
    union { float f; unsigned u; } v; v.f = f;
    unsigned r = v.u + 0x7fffu + ((v.u >> 16) & 1u);   // RNE
    return (short)(r >> 16);
}
__device__ __forceinline__ float sigf(float x) {
    return __builtin_amdgcn_rcpf(1.0f + __builtin_amdgcn_exp2f(-1.442695041f * x));
}
__device__ __forceinline__ float tanh_fast(float x) {
    float xc = fminf(fmaxf(x, -15.0f), 15.0f);
    float e  = __builtin_amdgcn_exp2f(2.885390082f * xc);
    return (e - 1.0f) * __builtin_amdgcn_rcpf(e + 1.0f);
}

__global__ __launch_bounds__(512, 2)
void slstm_persistent(const float* __restrict__ x,
                      const float* __restrict__ W_ih,
                      const float* __restrict__ W_hh,
                      const float* __restrict__ b_ih,
                      const float* __restrict__ b_hh,
                      const float* __restrict__ fc_w,
                      const float* __restrict__ fc_b,
                      float* __restrict__ out)
{
    // fragment-ordered h, double-buffered: [2][4 kf][4 quad][16 c16][8 j] bf16 = 16 KB
    __shared__ __align__(16) unsigned short h_frag[2][4096];
    __shared__ float red[16];

    const int tid  = threadIdx.x;
    const int lane = tid & 63;
    const int wv   = tid >> 6;          // wave 0..7
    const int c16  = lane & 15;         // batch row within tile (B-frag n / D col)
    const int quad = lane >> 4;         // 0..3
    const int b0   = blockIdx.x * 16;

    // ---- A-operand (weights): wfrag[g][kf] = W'[gate][kf*32+quad*8+j], gate=128g+wv*16+c16
    // (bit-identical data to R1's B-frags; A/B lane layouts are symmetric) ----
    s16x8 wfrag[4][5];
    float bias[4][4];                   // bias[g][r], gate row = 128g + wv*16 + quad*4 + r
    #pragma unroll
    for (int g = 0; g < 4; ++g) {
        const int n = g * 128 + wv * 16 + c16;
        #pragma unroll
        for (int kf = 0; kf < 5; ++kf) {
            s16x8 fr;
            #pragma unroll
            for (int j = 0; j < 8; ++j) {
                const int k = kf * 32 + quad * 8 + j;
                float v;
                if (kf < 4) v = W_hh[n * H_DIM + k];
                else {
                    const int kk = k - H_DIM;
                    v = (kk < IN_DIM) ? W_ih[n * IN_DIM + kk] : 0.0f;
                }
                fr[j] = f2bf(v);
            }
            wfrag[g][kf] = fr;
        }
        #pragma unroll
        for (int r = 0; r < 4; ++r) {
            const int m = g * 128 + wv * 16 + quad * 4 + r;
            bias[g][r] = b_ih[m] + b_hh[m];
        }
    }

    // ---- init h0 = 0 in both buffers; zero reduction slots ----
    for (int i = tid; i < 2 * 4096; i += 512)
        ((unsigned short*)h_frag)[i] = 0;
    if (tid < 16) red[tid] = 0.0f;

    float c_st[4] = {0.f, 0.f, 0.f, 0.f};
    float hreg[4] = {0.f, 0.f, 0.f, 0.f};

    // ---- x prefetch (t=0): lane supplies x[b0+c16][t][q01*8 .. +7] (quad>=2 lanes unused)
    const float* xrow = x + (size_t)(b0 + c16) * (size_t)(T_LEN * IN_DIM);
    const int q01 = quad & 1;
    f32x4 px0 = *(const f32x4*)(xrow + q01 * 8);
    f32x4 px1 = *(const f32x4*)(xrow + q01 * 8 + 4);

    // write-address constants (fragment-order position of this lane's 4 h values)
    const int kfw   = wv >> 1;
    const int quadw = (wv & 1) * 2 + (quad >> 1);
    const int widx  = ((kfw * 4 + quadw) * 16 + c16) * 8 + (quad & 1) * 4;

    __syncthreads();

    for (int t = 0; t < T_LEN; ++t) {
        const int buf = t & 1;

        // B-frags: h from LDS, lane-contiguous 16B -> conflict-free ds_read_b128
        s16x8 zf[5];
        #pragma unroll
        for (int kf = 0; kf < 4; ++kf)
            zf[kf] = *(const s16x8*)&h_frag[buf][(kf * 4 + quad) * 128 + c16 * 8];
        {
            s16x8 xf;
            #pragma unroll
            for (int j = 0; j < 4; ++j) {
                xf[j]     = (quad < 2) ? f2bf(px0[j]) : (short)0;
                xf[j + 4] = (quad < 2) ? f2bf(px1[j]) : (short)0;
            }
            zf[4] = xf;
        }

        // prefetch next timestep (hidden behind MFMAs)
        const int tn = (t + 1 < T_LEN) ? (t + 1) : (T_LEN - 1);
        px0 = *(const f32x4*)(xrow + tn * IN_DIM + q01 * 8);
        px1 = *(const f32x4*)(xrow + tn * IN_DIM + q01 * 8 + 4);

        // gates^T: acc[g] = bias + W' @ [h|x]^T -- 20 MFMAs, 4 independent chains
        f32x4 acc[4];
        #pragma unroll
        for (int g = 0; g < 4; ++g) {
            f32x4 a; a[0] = bias[g][0]; a[1] = bias[g][1]; a[2] = bias[g][2]; a[3] = bias[g][3];
            acc[g] = a;
        }
        #pragma unroll
        for (int kf = 0; kf < 5; ++kf)
            #pragma unroll
            for (int g = 0; g < 4; ++g)
                acc[g] = __builtin_amdgcn_mfma_f32_16x16x32_bf16(wfrag[g][kf], zf[kf], acc[g], 0, 0, 0);

        // elementwise LSTM update in registers.
        // Lane owns batch=c16, h-cols wv*16+quad*4+r (r=0..3) -> 4 consecutive cols.
        s16x4 hv;
        #pragma unroll
        for (int r = 0; r < 4; ++r) {
            const float ig = acc[0][r], fg = acc[1][r], gg = acc[2][r], og = acc[3][r];
            const float cn = sigf(fg) * c_st[r] + sigf(ig) * tanh_fast(gg);
            c_st[r] = cn;
            const float hn = sigf(og) * tanh_fast(cn);
            hreg[r] = hn;
            hv[r] = f2bf(hn);
        }
        *(s16x4*)&h_frag[buf ^ 1][widx] = hv;   // one ds_write_b64, conflict-free
        __syncthreads();
    }

    // ---- epilogue: out[b] = sum_col h[b][col] * fc_w[col] + fc_b ----
    float v = 0.0f;
    #pragma unroll
    for (int r = 0; r < 4; ++r)
        v += hreg[r] * fc_w[wv * 16 + quad * 4 + r];
    v += __shfl_xor(v, 16);
    v += __shfl_xor(v, 32);                     // reduce over quad (same c16)
    if (lane < 16) atomicAdd(&red[c16], v);     // combine 8 waves
    __syncthreads();
    if (tid < 16) out[b0 + tid] = red[tid] + fc_b[0];
}

extern "C" void kernel_launch(void* const* d_in, const int* in_sizes, int n_in,
                              void* d_out, int out_size, void* d_ws, size_t ws_size,
                              hipStream_t stream) {
    const float* x    = (const float*)d_in[0];
    const float* W_ih = (const float*)d_in[1];
    const float* W_hh = (const float*)d_in[2];
    const float* b_ih = (const float*)d_in[3];
    const float* b_hh = (const float*)d_in[4];
    const float* fc_w = (const float*)d_in[5];
    const float* fc_b = (const float*)d_in[6];
    float* out = (float*)d_out;

    slstm_persistent<<<64, 512, 0, stream>>>(x, W_ih, W_hh, b_ih, b_hh, fc_w, fc_b, out);
}